// Round 5
// baseline (222.355 us; speedup 1.0000x reference)
//
#include <hip/hip_runtime.h>
#include <hip/hip_bf16.h>

// QuaternionLSTMCell on MI355X (gfx950). B=2048, I=512, H=512.
//
// Round 5: R4 skeleton (pack + fused gemm_cell, 3-slot counted-vmcnt
// pipeline, XCD-rectangle swizzle, pre-swizzled bank-conflict-free layout)
// with the K-loop restructured into the m201-style 4-phase-per-K-tile
// cadence: each phase {ds_read frag subset; issue stage loads; s_barrier;
// lgkmcnt(0)+sched_barrier; setprio(1); 8 MFMA; setprio(0); s_barrier}.
// Creates cross-wave role-split so ds_read latency hides under other
// waves' MFMA (T3 prerequisite for T2/T4/T5 per the technique catalog).

#define BDIM 256
#define GDIM 512

typedef __attribute__((ext_vector_type(8))) short short8;
typedef __attribute__((ext_vector_type(4))) float f32x4;

typedef const __attribute__((address_space(1))) void* gptr_t;
typedef __attribute__((address_space(3))) void* lptr_t;

__device__ __forceinline__ ushort f2b(float f) {
  __hip_bfloat16 h = __float2bfloat16(f);
  union { __hip_bfloat16 b; ushort u; } cv;
  cv.b = h;
  return cv.u;
}

// ---------------------------------------------------------------------------
// pack_kernel: blocks [0,2048) build A; blocks [2048,10240) build Wp.
// Swizzle: destination column = col ^ ((row&7)<<3)  (16B chunks permuted
// within each 64-element K-window).
// ---------------------------------------------------------------------------
__global__ __launch_bounds__(BDIM) void pack_kernel(
    const float* __restrict__ x, const float* __restrict__ h,
    const float* __restrict__ w0, const float* __restrict__ w1,
    const float* __restrict__ w2, const float* __restrict__ w3,
    const float* __restrict__ u0, const float* __restrict__ u1,
    const float* __restrict__ u2, const float* __restrict__ u3,
    ushort* __restrict__ A, ushort* __restrict__ Wp) {
  if (blockIdx.x < 2048) {
    int tid = blockIdx.x * BDIM + threadIdx.x;
    int b = tid >> 8;
    int pos0 = (tid & 255) << 2;                   // 0..1020 step 4
    const float* src = (pos0 < 512)
        ? (x + ((size_t)b * 512 + pos0) * 4)
        : (h + ((size_t)b * 512 + (pos0 - 512)) * 4);
    float4 q0 = reinterpret_cast<const float4*>(src)[0];
    float4 q1 = reinterpret_cast<const float4*>(src)[1];
    float4 q2 = reinterpret_cast<const float4*>(src)[2];
    float4 q3 = reinterpret_cast<const float4*>(src)[3];
    int swz = (b & 7) << 3;
    ushort* Ab = A + (size_t)b * 4096 + (pos0 ^ swz);
    union { ushort u[4]; uint2 v; } r0, r1, r2, r3;
    r0.u[0] = f2b(q0.x); r0.u[1] = f2b(q1.x); r0.u[2] = f2b(q2.x); r0.u[3] = f2b(q3.x);
    r1.u[0] = f2b(q0.y); r1.u[1] = f2b(q1.y); r1.u[2] = f2b(q2.y); r1.u[3] = f2b(q3.y);
    r2.u[0] = f2b(q0.z); r2.u[1] = f2b(q1.z); r2.u[2] = f2b(q2.z); r2.u[3] = f2b(q3.z);
    r3.u[0] = f2b(q0.w); r3.u[1] = f2b(q1.w); r3.u[2] = f2b(q2.w); r3.u[3] = f2b(q3.w);
    *reinterpret_cast<uint2*>(Ab)        = r0.v;
    *reinterpret_cast<uint2*>(Ab + 1024) = r1.v;
    *reinterpret_cast<uint2*>(Ab + 2048) = r2.v;
    *reinterpret_cast<uint2*>(Ab + 3072) = r3.v;
  } else {
    int tid = (blockIdx.x - 2048) * BDIM + threadIdx.x;
    int n = tid >> 9;                    // 0..4095
    int k = (tid & 511) << 3;            // 0..4088
    int swz = (n & 7) << 3;
    ushort* dst = Wp + (size_t)n * 4096 + (k ^ swz);
    int o = n >> 3, g = n & 7;
    if (g == 7) {
      uint4 z = {0u, 0u, 0u, 0u};
      *reinterpret_cast<uint4*>(dst) = z;
      return;
    }
    int cin = k >> 10, pos = k & 1023;
    int part = pos >> 9, ii = pos & 511;
    int gi = (g < 3) ? g : 3;
    int co = (g < 3) ? 0 : g - 3;
    int comp = cin ^ co;
    float sg = ((0x5390u >> ((cin << 2) | co)) & 1u) ? -1.0f : 1.0f;
    const float* base;
    if (part == 0) base = (gi == 0) ? w0 : (gi == 1) ? w1 : (gi == 2) ? w2 : w3;
    else           base = (gi == 0) ? u0 : (gi == 1) ? u1 : (gi == 2) ? u2 : u3;
    const float* p = base + (size_t)comp * 262144 + (size_t)o * 512 + ii;
    float4 v0 = *reinterpret_cast<const float4*>(p);
    float4 v1 = *reinterpret_cast<const float4*>(p + 4);
    union { ushort u[8]; uint4 v; } r;
    r.u[0] = f2b(sg * v0.x); r.u[1] = f2b(sg * v0.y);
    r.u[2] = f2b(sg * v0.z); r.u[3] = f2b(sg * v0.w);
    r.u[4] = f2b(sg * v1.x); r.u[5] = f2b(sg * v1.y);
    r.u[6] = f2b(sg * v1.z); r.u[7] = f2b(sg * v1.w);
    *reinterpret_cast<uint4*>(dst) = r.v;
  }
}

// ---------------------------------------------------------------------------
// gemm_cell: pre = A @ Wp^T, fused LSTM cell. 4-phase K-loop.
// ---------------------------------------------------------------------------
__global__ __launch_bounds__(GDIM, 2) void gemm_cell_kernel(
    const ushort* __restrict__ A, const ushort* __restrict__ Wp,
    const float* __restrict__ cin_, const float* __restrict__ bi,
    const float* __restrict__ bfg, const float* __restrict__ bo,
    const float* __restrict__ bc, float* __restrict__ out) {
  // LDS: As 3 slots x [128][64] (16KB), Bs 3 slots x [256][64] (32KB) = 144KB
  __shared__ ushort SMEM[73728];
  ushort* As = SMEM;              // slot s at As + s*8192
  ushort* Bs = SMEM + 24576;      // slot s at Bs + s*16384

  const int t = threadIdx.x;
  const int lane = t & 63;
  const int wid = t >> 6;
  const int wm = wid >> 2;              // 0..1
  const int wn = wid & 3;               // 0..3
  const int lrow = lane & 15;
  const int lk8 = (lane >> 4) << 3;     // 0,8,16,24
  const int swzE = (lrow & 7) << 3;

  // XCD-rectangle swizzle: 8bx x 4by per XCD (bijective)
  const int bid = blockIdx.x;           // 0..255
  const int xcd = bid & 7;
  const int loc = bid >> 3;             // 0..31
  const int bx = (xcd & 1) * 8 + (loc & 7);    // 0..15
  const int by = (xcd >> 1) * 4 + (loc >> 3);  // 0..15
  const int m0 = by * 128;
  const int n0 = bx * 256;

  f32x4 acc[4][4];
#pragma unroll
  for (int mi = 0; mi < 4; ++mi)
#pragma unroll
    for (int ni = 0; ni < 4; ++ni)
      acc[mi][ni] = (f32x4){0.f, 0.f, 0.f, 0.f};

  const ushort* Ag = A + (size_t)m0 * 4096;
  const ushort* Bg = Wp + (size_t)n0 * 4096;
  const int c8 = (t & 7) << 3;

#define STAGE_A(KT, S, I)                                                     \
  {                                                                           \
    int j = t + (I) * 512;                                                    \
    __builtin_amdgcn_global_load_lds(                                         \
        (gptr_t)(Ag + (size_t)(j >> 3) * 4096 + (KT) * 64 + c8),              \
        (lptr_t)(As + (S) * 8192 + j * 8), 16, 0, 0);                         \
  }
#define STAGE_B(KT, S, I)                                                     \
  {                                                                           \
    int j = t + (I) * 512;                                                    \
    __builtin_amdgcn_global_load_lds(                                         \
        (gptr_t)(Bg + (size_t)(j >> 3) * 4096 + (KT) * 64 + c8),              \
        (lptr_t)(Bs + (S) * 16384 + j * 8), 16, 0, 0);                        \
  }
#define LDA(MI, CC) (*reinterpret_cast<const short8*>(                        \
    Ac + (wm * 64 + (MI) * 16 + lrow) * 64 + (CC)))
#define LDB(NI, CC) (*reinterpret_cast<const short8*>(                        \
    Bc + (wn * 64 + (NI) * 16 + lrow) * 64 + (CC)))
#define MFMA(AV, BV, ACC)                                                     \
  ACC = __builtin_amdgcn_mfma_f32_16x16x32_bf16((AV), (BV), (ACC), 0, 0, 0);
#define PHASE_SYNC()                                                          \
  __builtin_amdgcn_s_barrier();                                               \
  asm volatile("s_waitcnt lgkmcnt(0)" ::: "memory");                          \
  __builtin_amdgcn_sched_barrier(0);

  // prologue: stage kt=0 -> slot0, kt=1 -> slot1
  STAGE_A(0, 0, 0) STAGE_A(0, 0, 1)
  STAGE_B(0, 0, 0) STAGE_B(0, 0, 1) STAGE_B(0, 0, 2) STAGE_B(0, 0, 3)
  STAGE_A(1, 1, 0) STAGE_A(1, 1, 1)
  STAGE_B(1, 1, 0) STAGE_B(1, 1, 1) STAGE_B(1, 1, 2) STAGE_B(1, 1, 3)
  asm volatile("s_waitcnt vmcnt(6)" ::: "memory");
  __builtin_amdgcn_s_barrier();
  __builtin_amdgcn_sched_barrier(0);

  int cur = 0;
  for (int kt = 0; kt < 64; ++kt) {
    const int pf = (kt < 62);
    const int ps = (cur >= 1) ? cur - 1 : 2;     // (cur+2)%3
    const ushort* Ac = As + cur * 8192;
    const ushort* Bc = Bs + cur * 16384;
    const int c0 = lk8 ^ swzE;
    const int c1 = (32 + lk8) ^ swzE;
    short8 a0, a1, a2, a3, b0, b1, b2, b3;

    // ---- P0: kk0 A-frags + B0,B1; MFMA cols 0,1 ----
    a0 = LDA(0, c0); a1 = LDA(1, c0); a2 = LDA(2, c0); a3 = LDA(3, c0);
    b0 = LDB(0, c0); b1 = LDB(1, c0);
    if (pf) { STAGE_A(kt + 2, ps, 0) STAGE_A(kt + 2, ps, 1) }
    PHASE_SYNC();
    __builtin_amdgcn_s_setprio(1);
    MFMA(a0, b0, acc[0][0]) MFMA(a1, b0, acc[1][0])
    MFMA(a2, b0, acc[2][0]) MFMA(a3, b0, acc[3][0])
    MFMA(a0, b1, acc[0][1]) MFMA(a1, b1, acc[1][1])
    MFMA(a2, b1, acc[2][1]) MFMA(a3, b1, acc[3][1])
    __builtin_amdgcn_s_setprio(0);
    __builtin_amdgcn_s_barrier();

    // ---- P1: kk0 B2,B3; MFMA cols 2,3 ----
    b2 = LDB(2, c0); b3 = LDB(3, c0);
    if (pf) { STAGE_B(kt + 2, ps, 0) STAGE_B(kt + 2, ps, 1) }
    PHASE_SYNC();
    __builtin_amdgcn_s_setprio(1);
    MFMA(a0, b2, acc[0][2]) MFMA(a1, b2, acc[1][2])
    MFMA(a2, b2, acc[2][2]) MFMA(a3, b2, acc[3][2])
    MFMA(a0, b3, acc[0][3]) MFMA(a1, b3, acc[1][3])
    MFMA(a2, b3, acc[2][3]) MFMA(a3, b3, acc[3][3])
    __builtin_amdgcn_s_setprio(0);
    __builtin_amdgcn_s_barrier();

    // ---- P2: kk1 A-frags + B0,B1; MFMA cols 0,1 ----
    a0 = LDA(0, c1); a1 = LDA(1, c1); a2 = LDA(2, c1); a3 = LDA(3, c1);
    b0 = LDB(0, c1); b1 = LDB(1, c1);
    if (pf) { STAGE_B(kt + 2, ps, 2) }
    PHASE_SYNC();
    __builtin_amdgcn_s_setprio(1);
    MFMA(a0, b0, acc[0][0]) MFMA(a1, b0, acc[1][0])
    MFMA(a2, b0, acc[2][0]) MFMA(a3, b0, acc[3][0])
    MFMA(a0, b1, acc[0][1]) MFMA(a1, b1, acc[1][1])
    MFMA(a2, b1, acc[2][1]) MFMA(a3, b1, acc[3][1])
    __builtin_amdgcn_s_setprio(0);
    __builtin_amdgcn_s_barrier();

    // ---- P3: kk1 B2,B3; MFMA cols 2,3; per-K-tile vmcnt ----
    b2 = LDB(2, c1); b3 = LDB(3, c1);
    if (pf) { STAGE_B(kt + 2, ps, 3) }
    PHASE_SYNC();
    __builtin_amdgcn_s_setprio(1);
    MFMA(a0, b2, acc[0][2]) MFMA(a1, b2, acc[1][2])
    MFMA(a2, b2, acc[2][2]) MFMA(a3, b2, acc[3][2])
    MFMA(a0, b3, acc[0][3]) MFMA(a1, b3, acc[1][3])
    MFMA(a2, b3, acc[2][3]) MFMA(a3, b3, acc[3][3])
    __builtin_amdgcn_s_setprio(0);
    if (kt < 62)       { asm volatile("s_waitcnt vmcnt(6)" ::: "memory"); }
    else if (kt == 62) { asm volatile("s_waitcnt vmcnt(0)" ::: "memory"); }
    __builtin_amdgcn_s_barrier();
    __builtin_amdgcn_sched_barrier(0);
    cur = (cur == 2) ? 0 : cur + 1;
  }
  __syncthreads();   // full drain before aliasing LDS for the epilogue

  // ---- fused LSTM cell epilogue (unchanged from R4) ----
  float* Es = (float*)SMEM;
  const int o0 = bx * 32;
  const int lr4 = (lane >> 4) << 2;     // 0,4,8,12

#pragma unroll
  for (int wmc = 0; wmc < 2; ++wmc) {
#pragma unroll
    for (int mi = 0; mi < 4; ++mi) {
      if (wm == wmc) {
#pragma unroll
        for (int ni = 0; ni < 4; ++ni) {
          float* dst = Es + lr4 * 260 + wn * 64 + ni * 16 + lrow;
#pragma unroll
          for (int r = 0; r < 4; ++r) dst[r * 260] = acc[mi][ni][r];
        }
      }
      __syncthreads();
      {
        int bl = t >> 5;                // 0..15
        int ol = t & 31;                // 0..31
        const float* e = Es + bl * 260 + ol * 8;
        int b = m0 + wmc * 64 + mi * 16 + bl;
        int o = o0 + ol;
        float4 bcv = *reinterpret_cast<const float4*>(bc + (size_t)o * 4);
        float ip = e[0] + bi[o << 2];
        float fp = e[1] + bfg[o << 2];
        float op = e[2] + bo[o << 2];
        float g0 = tanhf(e[3] + bcv.x);
        float g1 = tanhf(e[4] + bcv.y);
        float g2 = tanhf(e[5] + bcv.z);
        float g3 = tanhf(e[6] + bcv.w);
        float ig = 1.f / (1.f + expf(-ip));
        float fg = 1.f / (1.f + expf(-fp));
        float og = 1.f / (1.f + expf(-op));
        float4 cv = *reinterpret_cast<const float4*>(cin_ + ((size_t)b * 512 + o) * 4);
        float4 ct, ht;
        ct.x = fg * cv.x + ig * g0;  ht.x = og * tanhf(ct.x);
        ct.y = fg * cv.y + ig * g1;  ht.y = og * tanhf(ct.y);
        ct.z = fg * cv.z + ig * g2;  ht.z = og * tanhf(ct.z);
        ct.w = fg * cv.w + ig * g3;  ht.w = og * tanhf(ct.w);
        *reinterpret_cast<float4*>(out + ((size_t)b * 512 + o) * 4) = ht;
        *reinterpret_cast<float4*>(out + 4194304 + ((size_t)b * 512 + o) * 4) = ct;
      }
      __syncthreads();
    }
  }
#undef STAGE_A
#undef STAGE_B
#undef LDA
#undef LDB
#undef MFMA
#undef PHASE_SYNC
}

// ---------------------------------------------------------------------------
extern "C" void kernel_launch(void* const* d_in, const int* in_sizes, int n_in,
                              void* d_out, int out_size, void* d_ws, size_t ws_size,
                              hipStream_t stream) {
  const float* x   = (const float*)d_in[0];
  const float* h   = (const float*)d_in[1];
  const float* c   = (const float*)d_in[2];
  const float* wi  = (const float*)d_in[3];
  const float* wf  = (const float*)d_in[4];
  const float* wo  = (const float*)d_in[5];
  const float* wc  = (const float*)d_in[6];
  const float* ui  = (const float*)d_in[7];
  const float* uf  = (const float*)d_in[8];
  const float* uo  = (const float*)d_in[9];
  const float* uc  = (const float*)d_in[10];
  const float* bi  = (const float*)d_in[11];
  const float* bf_ = (const float*)d_in[12];
  const float* bo  = (const float*)d_in[13];
  const float* bc  = (const float*)d_in[14];
  float* out = (float*)d_out;

  ushort* A  = (ushort*)d_ws;                                  // 16 MB
  ushort* Wp = (ushort*)((char*)d_ws + (size_t)16777216);      // 32 MB

  hipLaunchKernelGGL(pack_kernel, dim3(10240), dim3(BDIM), 0, stream,
                     x, h, wi, wf, wo, wc, ui, uf, uo, uc, A, Wp);
  hipLaunchKernelGGL(gemm_cell_kernel, dim3(256), dim3(GDIM), 0, stream,
                     A, Wp, c, bi, bf_, bo, bc, out);
}